// Round 2
// baseline (5292.411 us; speedup 1.0000x reference)
//
#include <hip/hip_runtime.h>
#include <hip/hip_bf16.h>

#define T_STEPS 100
#define NB 256
#define CIN 700
#define HID 1024
#define NCLS 20
#define NH (NB * HID)                 // 262144
#define TNH ((long)T_STEPS * NH)      // 26,214,400

// ---------------------------------------------------------------------------
// Big GEMM: A [M x K] row-major, B [K x 1024] row-major, out = A@B + bias.
// 64x64 tile, BK=32, 256 threads, 4x4 per thread.
// MODE 0: out[r*HID + h]            (feat @ W3 -> y)
// MODE 1: r = n*T + t  -> out[t*NB*HID + n*HID + h]   (x @ W_in -> xin[t][n][h])
// ---------------------------------------------------------------------------
template <int MODE>
__global__ __launch_bounds__(256) void gemm_big(
    const float* __restrict__ A, const float* __restrict__ B,
    const float* __restrict__ bias, float* __restrict__ out, int K) {
  __shared__ float As[32][68];  // [k][m], pad 4 -> 272B row stride (16B aligned)
  __shared__ float Bs[32][68];  // [k][n]
  const int tid = threadIdx.x;
  const int tx = tid & 15, ty = tid >> 4;
  const long row0 = (long)blockIdx.x * 64;
  const int col0 = blockIdx.y * 64;
  float acc[4][4] = {};

  for (int kt = 0; kt < K; kt += 32) {
    // A tile: 64 rows x 32 k  (512 float4, 2 per thread), transpose into As[k][m]
#pragma unroll
    for (int i = 0; i < 2; ++i) {
      int f = tid + 256 * i;
      int m = f >> 3;
      int k4 = (f & 7) * 4;
      float4 v = make_float4(0.f, 0.f, 0.f, 0.f);
      if (kt + k4 < K) v = *(const float4*)(A + (row0 + m) * (long)K + kt + k4);
      As[k4 + 0][m] = v.x;
      As[k4 + 1][m] = v.y;
      As[k4 + 2][m] = v.z;
      As[k4 + 3][m] = v.w;
    }
    // B tile: 32 k x 64 n (512 float4, 2 per thread)
#pragma unroll
    for (int i = 0; i < 2; ++i) {
      int f = tid + 256 * i;
      int k = f >> 4;
      int n4 = (f & 15) * 4;
      float4 v = make_float4(0.f, 0.f, 0.f, 0.f);
      int kk = kt + k;
      if (kk < K) v = *(const float4*)(B + (long)kk * HID + col0 + n4);
      *(float4*)&Bs[k][n4] = v;
    }
    __syncthreads();
#pragma unroll
    for (int k = 0; k < 32; ++k) {
      float a[4], b[4];
#pragma unroll
      for (int i = 0; i < 4; ++i) a[i] = As[k][ty * 4 + i];
#pragma unroll
      for (int j = 0; j < 4; ++j) b[j] = Bs[k][tx * 4 + j];
#pragma unroll
      for (int i = 0; i < 4; ++i)
#pragma unroll
        for (int j = 0; j < 4; ++j) acc[i][j] += a[i] * b[j];
    }
    __syncthreads();
  }

#pragma unroll
  for (int i = 0; i < 4; ++i) {
    long r = row0 + ty * 4 + i;
#pragma unroll
    for (int j = 0; j < 4; ++j) {
      int h = col0 + tx * 4 + j;
      float val = acc[i][j] + bias[h];
      if (MODE == 0) {
        out[r * HID + h] = val;
      } else {
        int t = (int)(r % T_STEPS);
        int n = (int)(r / T_STEPS);
        out[((long)t * NB + n) * HID + h] = val;
      }
    }
  }
}

// ---------------------------------------------------------------------------
// Recurrent step: g = s_in @ Wcat,  Wcat = [W_rec | W2]  (1024 x 2048).
// cols < 1024: inp = g + b_rec + xin_next -> LIF1 -> (v1, s_next)
// cols >=1024: z = g + b2              -> LIF2 -> (v2, feat_t)
// BM=32 (batch), BN=64, BK=32; 256 threads, 2x4 per thread; grid (8,32)=256 WGs.
// ---------------------------------------------------------------------------
__global__ __launch_bounds__(256) void step_kernel(
    const float* __restrict__ s_in, const float* __restrict__ Wcat,
    const float* __restrict__ b_rec, const float* __restrict__ b2,
    const float* __restrict__ xin_next, float* __restrict__ v1,
    float* __restrict__ v2, float* __restrict__ s_next,
    float* __restrict__ feat_t, int write_rec) {
  __shared__ float As[32][36];  // [k][m], 144B row stride
  __shared__ float Bs[32][68];  // [k][n]
  const int tid = threadIdx.x;
  const int tx = tid & 15, ty = tid >> 4;
  const int row0 = blockIdx.x * 32;
  const int col0 = blockIdx.y * 64;
  float acc[2][4] = {};

  for (int kt = 0; kt < HID; kt += 32) {
    // A tile: 32 rows x 32 k (256 float4, 1 per thread)
    {
      int m = tid >> 3;
      int k4 = (tid & 7) * 4;
      float4 v = *(const float4*)(s_in + (long)(row0 + m) * HID + kt + k4);
      As[k4 + 0][m] = v.x;
      As[k4 + 1][m] = v.y;
      As[k4 + 2][m] = v.z;
      As[k4 + 3][m] = v.w;
    }
    // B tile: 32 k x 64 n (512 float4, 2 per thread); Wcat stride 2048
#pragma unroll
    for (int i = 0; i < 2; ++i) {
      int f = tid + 256 * i;
      int k = f >> 4;
      int n4 = (f & 15) * 4;
      float4 v = *(const float4*)(Wcat + (long)(kt + k) * 2048 + col0 + n4);
      *(float4*)&Bs[k][n4] = v;
    }
    __syncthreads();
#pragma unroll
    for (int k = 0; k < 32; ++k) {
      float a0 = As[k][ty * 2];
      float a1 = As[k][ty * 2 + 1];
      float b[4];
#pragma unroll
      for (int j = 0; j < 4; ++j) b[j] = Bs[k][tx * 4 + j];
#pragma unroll
      for (int j = 0; j < 4; ++j) {
        acc[0][j] += a0 * b[j];
        acc[1][j] += a1 * b[j];
      }
    }
    __syncthreads();
  }

  const bool is_rec = (col0 < HID);  // uniform per workgroup
#pragma unroll
  for (int i = 0; i < 2; ++i) {
    int n = row0 + ty * 2 + i;
#pragma unroll
    for (int j = 0; j < 4; ++j) {
      int c = col0 + tx * 4 + j;
      if (is_rec) {
        long idx = (long)n * HID + c;
        float val = acc[i][j] + b_rec[c] + xin_next[idx];
        float v = v1[idx];
        float h = v + (val - v) * 0.5f;
        if (write_rec) {
          v1[idx] = (h >= 1.0f) ? 0.0f : h;
          s_next[idx] = (h >= 1.0f) ? 1.0f : 0.0f;
        }
      } else {
        int hcol = c - HID;
        long idx = (long)n * HID + hcol;
        float val = acc[i][j] + b2[hcol];
        float v = v2[idx];
        float h = v + (val - v) * 0.5f;
        v2[idx] = (h >= 1.0f) ? 0.0f : h;
        feat_t[idx] = (h >= 1.0f) ? 1.0f : 0.0f;
      }
    }
  }
}

// ---------------------------------------------------------------------------
__global__ __launch_bounds__(256) void build_wcat(
    const float* __restrict__ Wrec, const float* __restrict__ W2,
    float* __restrict__ Wcat) {
  long i = (long)blockIdx.x * 256 + threadIdx.x;  // over 1024*1024
  long k = i >> 10, j = i & 1023;
  Wcat[k * 2048 + j] = Wrec[i];
  Wcat[k * 2048 + HID + j] = W2[i];
}

__global__ __launch_bounds__(256) void zero_kernel(float* __restrict__ p) {
  p[(long)blockIdx.x * 256 + threadIdx.x] = 0.0f;
}

// LIF1 at t=0: inp = xin[0] + b_rec, v1 starts at 0.
__global__ __launch_bounds__(256) void lif_prologue(
    const float* __restrict__ xin0, const float* __restrict__ b_rec,
    float* __restrict__ v1, float* __restrict__ s0) {
  long id = (long)blockIdx.x * 256 + threadIdx.x;
  float inp = xin0[id] + b_rec[id & (HID - 1)];
  float h = inp * 0.5f;
  v1[id] = (h >= 1.0f) ? 0.0f : h;
  s0[id] = (h >= 1.0f) ? 1.0f : 0.0f;
}

// LayerNorm over last dim (1024), in place. One block (256 thr) per row.
__global__ __launch_bounds__(256) void ln_kernel(float* __restrict__ y,
                                                 const float* __restrict__ g,
                                                 const float* __restrict__ b) {
  __shared__ float red[4];
  long row = blockIdx.x;
  float* p = y + row * HID;
  int tid = threadIdx.x;
  float x[4];
#pragma unroll
  for (int i = 0; i < 4; ++i) x[i] = p[tid + 256 * i];
  float s = x[0] + x[1] + x[2] + x[3];
#pragma unroll
  for (int m = 32; m; m >>= 1) s += __shfl_xor(s, m, 64);
  if ((tid & 63) == 0) red[tid >> 6] = s;
  __syncthreads();
  float mu = (red[0] + red[1] + red[2] + red[3]) * (1.0f / HID);
  __syncthreads();
  float r0 = x[0] - mu, r1 = x[1] - mu, r2 = x[2] - mu, r3 = x[3] - mu;
  float v = r0 * r0 + r1 * r1 + r2 * r2 + r3 * r3;
#pragma unroll
  for (int m = 32; m; m >>= 1) v += __shfl_xor(v, m, 64);
  if ((tid & 63) == 0) red[tid >> 6] = v;
  __syncthreads();
  float var = (red[0] + red[1] + red[2] + red[3]) * (1.0f / HID);
  float inv = 1.0f / sqrtf(var + 1e-5f);
#pragma unroll
  for (int i = 0; i < 4; ++i) {
    int h = tid + 256 * i;
    p[h] = (x[i] - mu) * inv * g[h] + b[h];
  }
}

// Third LIF over T (sequential in-thread) fused with mean over T.
__global__ __launch_bounds__(256) void lifc_kernel(
    const float* __restrict__ y, float* __restrict__ sbar) {
  long id = (long)blockIdx.x * 256 + threadIdx.x;  // < NB*HID
  float v = 0.0f, acc = 0.0f;
  for (int t = 0; t < T_STEPS; ++t) {
    float x = y[(long)t * NH + id];
    float h = v + (x - v) * 0.5f;
    if (h >= 1.0f) {
      acc += 1.0f;
      v = 0.0f;
    } else {
      v = h;
    }
  }
  sbar[id] = acc * (1.0f / T_STEPS);
}

// out[n,j] = sbar[n,:] @ W_out[:,j] + b_out[j]
__global__ __launch_bounds__(64) void out_kernel(
    const float* __restrict__ sbar, const float* __restrict__ Wout,
    const float* __restrict__ bout, float* __restrict__ out) {
  int n = blockIdx.x, j = threadIdx.x;
  if (j >= NCLS) return;
  const float* s = sbar + (long)n * HID;
  float a0 = 0.f, a1 = 0.f, a2 = 0.f, a3 = 0.f;
  for (int k = 0; k < HID; k += 4) {
    a0 += s[k + 0] * Wout[(k + 0) * NCLS + j];
    a1 += s[k + 1] * Wout[(k + 1) * NCLS + j];
    a2 += s[k + 2] * Wout[(k + 2) * NCLS + j];
    a3 += s[k + 3] * Wout[(k + 3) * NCLS + j];
  }
  out[n * NCLS + j] = ((a0 + a1) + (a2 + a3)) + bout[j];
}

// ---------------------------------------------------------------------------
extern "C" void kernel_launch(void* const* d_in, const int* in_sizes, int n_in,
                              void* d_out, int out_size, void* d_ws,
                              size_t ws_size, hipStream_t stream) {
  const float* x = (const float*)d_in[0];
  const float* W_in = (const float*)d_in[1];
  const float* b_in = (const float*)d_in[2];
  const float* W_rec = (const float*)d_in[3];
  const float* b_rec = (const float*)d_in[4];
  const float* W2 = (const float*)d_in[5];
  const float* b2 = (const float*)d_in[6];
  const float* W3 = (const float*)d_in[7];
  const float* b3 = (const float*)d_in[8];
  const float* ln_g = (const float*)d_in[9];
  const float* ln_b = (const float*)d_in[10];
  const float* W_out = (const float*)d_in[11];
  const float* b_out = (const float*)d_in[12];
  float* out = (float*)d_out;

  char* ws = (char*)d_ws;
  size_t off = 0;
  auto carve = [&](size_t bytes) -> float* {
    float* p = (float*)(ws + off);
    off += (bytes + 255) & ~(size_t)255;
    return p;
  };
  float* xin = carve((size_t)TNH * 4);   // reused as y after the scan
  float* feat = carve((size_t)TNH * 4);  // spike features (0/1 as fp32)
  float* wcat = carve((size_t)HID * 2048 * 4);
  float* v1 = carve((size_t)NH * 4);
  float* v2 = carve((size_t)NH * 4);
  float* sA = carve((size_t)NH * 4);
  float* sB = carve((size_t)NH * 4);
  float* sbar = carve((size_t)NH * 4);
  (void)ws_size;
  (void)in_sizes;
  (void)n_in;
  (void)out_size;

  build_wcat<<<dim3(HID * HID / 256), 256, 0, stream>>>(W_rec, W2, wcat);
  zero_kernel<<<dim3(NH / 256), 256, 0, stream>>>(v2);

  // xin[t][n][h] = x @ W_in + b_in
  gemm_big<1><<<dim3(25600 / 64, HID / 64), 256, 0, stream>>>(x, W_in, b_in,
                                                              xin, CIN);
  // s1(0), v1 from inp(0) = xin(0) + b_rec
  lif_prologue<<<dim3(NH / 256), 256, 0, stream>>>(xin, b_rec, v1, sA);

  float* s_prev = sA;
  float* s_next = sB;
  for (int t = 0; t < T_STEPS; ++t) {
    const float* xin_next = xin + (size_t)((t + 1) % T_STEPS) * NH;
    step_kernel<<<dim3(NB / 32, 2048 / 64), 256, 0, stream>>>(
        s_prev, wcat, b_rec, b2, xin_next, v1, v2, s_next,
        feat + (size_t)t * NH, (t < T_STEPS - 1) ? 1 : 0);
    float* tmp = s_prev;
    s_prev = s_next;
    s_next = tmp;
  }

  // y = feat @ W3 + b3  (into xin buffer), then LayerNorm in place
  gemm_big<0><<<dim3(25600 / 64, HID / 64), 256, 0, stream>>>(feat, W3, b3,
                                                              xin, HID);
  ln_kernel<<<dim3(25600), 256, 0, stream>>>(xin, ln_g, ln_b);
  // third LIF over T fused with mean -> sbar
  lifc_kernel<<<dim3(NH / 256), 256, 0, stream>>>(xin, sbar);
  // out = sbar @ W_out + b_out
  out_kernel<<<dim3(NB), 64, 0, stream>>>(sbar, W_out, b_out, out);
}

// Round 4
// 2885.750 us; speedup vs baseline: 1.8340x; 1.8340x over previous
//
#include <hip/hip_runtime.h>

#define T_STEPS 100
#define NB 256
#define CIN 700
#define CINP 704
#define HID 1024
#define NCLS 20
#define NH (NB * HID)                 // 262144
#define TNH ((long)T_STEPS * NH)      // 26,214,400

typedef __attribute__((ext_vector_type(8))) short bf16x8;
typedef __attribute__((ext_vector_type(4))) float f32x4;

__device__ inline unsigned short f2bf(float f) {
  union { float f; unsigned int u; } c; c.f = f;
  unsigned int u = c.u;
  unsigned int r = (u + 0x7FFFu + ((u >> 16) & 1u)) >> 16;
  return (unsigned short)r;
}
__device__ inline float bf2f(unsigned short h) {
  union { unsigned int u; float f; } c; c.u = ((unsigned int)h) << 16; return c.f;
}
__device__ inline f32x4 mfma16(bf16x8 a, bf16x8 b, f32x4 c) {
  return __builtin_amdgcn_mfma_f32_16x16x32_bf16(a, b, c, 0, 0, 0);
}

// ---------------------------------------------------------------------------
// Transpose + exact 3-way bf16 split: W [K][1024] fp32 -> Wh/Wm/Wl [1024][KP]
// (K-contiguous), zero-padded to KP. W == hi+mid+lo exactly (8+8+8 mantissa).
// ---------------------------------------------------------------------------
__global__ __launch_bounds__(256) void split_w(
    const float* __restrict__ W, unsigned short* __restrict__ oh,
    unsigned short* __restrict__ om, unsigned short* __restrict__ ol,
    int K, int KP) {
  __shared__ float s[32][33];
  const int k0 = blockIdx.x * 32, n0 = blockIdx.y * 32;
  const int tx = threadIdx.x & 31, ty = threadIdx.x >> 5;  // 32 x 8
#pragma unroll
  for (int i = 0; i < 4; ++i) {
    int k = k0 + ty + 8 * i;
    s[ty + 8 * i][tx] = (k < K) ? W[(long)k * HID + n0 + tx] : 0.f;
  }
  __syncthreads();
#pragma unroll
  for (int i = 0; i < 4; ++i) {
    int n = n0 + ty + 8 * i;
    float f = s[tx][ty + 8 * i];
    unsigned short h = f2bf(f);
    float r1 = f - bf2f(h);
    unsigned short m = f2bf(r1);
    float r2 = r1 - bf2f(m);
    unsigned short l = f2bf(r2);
    long o = (long)n * KP + k0 + tx;
    oh[o] = h; om[o] = m; ol[o] = l;
  }
}

// ---------------------------------------------------------------------------
// GEMM (exact-A bf16): out[MxHID] = A[Mx1024](bf16 0/1) @ (Bh+Bm+Bl)^T + bias
// B stored [1024 n][1024 k] bf16. 128x128 tile, BK=32, 4 waves each 64x64.
// ---------------------------------------------------------------------------
__global__ __launch_bounds__(256) void gemm_sw3(
    const unsigned short* __restrict__ A, const unsigned short* __restrict__ Bh,
    const unsigned short* __restrict__ Bm, const unsigned short* __restrict__ Bl,
    const float* __restrict__ bias, float* __restrict__ out, int M) {
  __shared__ unsigned short As[128][40], Bhs[128][40], Bms[128][40],
      Bls[128][40];
  const int tid = threadIdx.x;
  const int w = tid >> 6, lane = tid & 63;
  const int wm = w >> 1, wn = w & 1;
  const int l15 = lane & 15, g = lane >> 4;
  const long row0 = (long)blockIdx.x * 128;
  const int col0 = blockIdx.y * 128;
  f32x4 acc[4][4];
  const f32x4 zf = {0.f, 0.f, 0.f, 0.f};
#pragma unroll
  for (int mi = 0; mi < 4; ++mi)
#pragma unroll
    for (int ni = 0; ni < 4; ++ni) acc[mi][ni] = zf;

  for (int kt = 0; kt < HID; kt += 32) {
#pragma unroll
    for (int i = 0; i < 2; ++i) {
      int slot = tid + 256 * i;          // 0..511
      int r = slot >> 2, kk = (slot & 3) * 8;
      *(uint4*)&As[r][kk] = *(const uint4*)(A + (row0 + r) * HID + kt + kk);
      long gi = (long)(col0 + r) * HID + kt + kk;
      *(uint4*)&Bhs[r][kk] = *(const uint4*)(Bh + gi);
      *(uint4*)&Bms[r][kk] = *(const uint4*)(Bm + gi);
      *(uint4*)&Bls[r][kk] = *(const uint4*)(Bl + gi);
    }
    __syncthreads();
    bf16x8 af[4];
#pragma unroll
    for (int mi = 0; mi < 4; ++mi)
      af[mi] = *(const bf16x8*)&As[wm * 64 + mi * 16 + l15][g * 8];
#pragma unroll
    for (int ni = 0; ni < 4; ++ni) {
      int r = wn * 64 + ni * 16 + l15;
      bf16x8 bb;
      bb = *(const bf16x8*)&Bhs[r][g * 8];
#pragma unroll
      for (int mi = 0; mi < 4; ++mi) acc[mi][ni] = mfma16(af[mi], bb, acc[mi][ni]);
      bb = *(const bf16x8*)&Bms[r][g * 8];
#pragma unroll
      for (int mi = 0; mi < 4; ++mi) acc[mi][ni] = mfma16(af[mi], bb, acc[mi][ni]);
      bb = *(const bf16x8*)&Bls[r][g * 8];
#pragma unroll
      for (int mi = 0; mi < 4; ++mi) acc[mi][ni] = mfma16(af[mi], bb, acc[mi][ni]);
    }
    __syncthreads();
  }
#pragma unroll
  for (int mi = 0; mi < 4; ++mi)
#pragma unroll
    for (int ni = 0; ni < 4; ++ni) {
      int c = col0 + wn * 64 + ni * 16 + l15;
      float b = bias[c];
#pragma unroll
      for (int reg = 0; reg < 4; ++reg) {
        long r = row0 + wm * 64 + mi * 16 + g * 4 + reg;
        out[r * HID + c] = acc[mi][ni][reg] + b;
      }
    }
}

// ---------------------------------------------------------------------------
// GEMM1: xin = x @ W_in + b_in.  A = x fp32 [25600][700], split 3-way in
// staging; B = W_in 3-split [1024][704]. 6 products (>=2^-16); fp32-accum.
// Epilogue scatters r=(n*100+t) -> xin[t][n][h].
// ---------------------------------------------------------------------------
__global__ __launch_bounds__(256) void gemm_x6(
    const float* __restrict__ X, const unsigned short* __restrict__ Bh,
    const unsigned short* __restrict__ Bm, const unsigned short* __restrict__ Bl,
    const float* __restrict__ bias, float* __restrict__ out) {
  __shared__ unsigned short Ahs[128][40], Ams[128][40], Als[128][40];
  __shared__ unsigned short Bhs[128][40], Bms[128][40], Bls[128][40];
  const int tid = threadIdx.x;
  const int w = tid >> 6, lane = tid & 63;
  const int wm = w >> 1, wn = w & 1;
  const int l15 = lane & 15, g = lane >> 4;
  const long row0 = (long)blockIdx.x * 128;
  const int col0 = blockIdx.y * 128;
  f32x4 acc[4][4];
  const f32x4 zf = {0.f, 0.f, 0.f, 0.f};
#pragma unroll
  for (int mi = 0; mi < 4; ++mi)
#pragma unroll
    for (int ni = 0; ni < 4; ++ni) acc[mi][ni] = zf;

  for (int kt = 0; kt < CINP; kt += 32) {
    // A: 128 rows x 32 k fp32 -> 1024 float4 slots, 4/thread, split to 3 LDS
#pragma unroll
    for (int i = 0; i < 4; ++i) {
      int slot = tid + 256 * i;              // 0..1023
      int r = slot >> 3, kq = (slot & 7) * 4;
      float4 v = make_float4(0.f, 0.f, 0.f, 0.f);
      if (kt + kq < CIN) v = *(const float4*)(X + (row0 + r) * (long)CIN + kt + kq);
      unsigned int h0, h1, m0, m1, l0, l1;
      {
        float f0 = v.x, f1 = v.y;
        unsigned short a = f2bf(f0), b = f2bf(f1);
        float ra = f0 - bf2f(a), rb = f1 - bf2f(b);
        unsigned short c = f2bf(ra), d = f2bf(rb);
        float sa = ra - bf2f(c), sb = rb - bf2f(d);
        h0 = (unsigned int)a | ((unsigned int)b << 16);
        m0 = (unsigned int)c | ((unsigned int)d << 16);
        l0 = (unsigned int)f2bf(sa) | ((unsigned int)f2bf(sb) << 16);
      }
      {
        float f0 = v.z, f1 = v.w;
        unsigned short a = f2bf(f0), b = f2bf(f1);
        float ra = f0 - bf2f(a), rb = f1 - bf2f(b);
        unsigned short c = f2bf(ra), d = f2bf(rb);
        float sa = ra - bf2f(c), sb = rb - bf2f(d);
        h1 = (unsigned int)a | ((unsigned int)b << 16);
        m1 = (unsigned int)c | ((unsigned int)d << 16);
        l1 = (unsigned int)f2bf(sa) | ((unsigned int)f2bf(sb) << 16);
      }
      uint2 uh = {h0, h1}, um = {m0, m1}, ul = {l0, l1};
      *(uint2*)&Ahs[r][kq] = uh;
      *(uint2*)&Ams[r][kq] = um;
      *(uint2*)&Als[r][kq] = ul;
    }
    // B: 3 planes, 512 16B-slots, 2/thread
#pragma unroll
    for (int i = 0; i < 2; ++i) {
      int slot = tid + 256 * i;
      int r = slot >> 2, kk = (slot & 3) * 8;
      long gi = (long)(col0 + r) * CINP + kt + kk;
      *(uint4*)&Bhs[r][kk] = *(const uint4*)(Bh + gi);
      *(uint4*)&Bms[r][kk] = *(const uint4*)(Bm + gi);
      *(uint4*)&Bls[r][kk] = *(const uint4*)(Bl + gi);
    }
    __syncthreads();
    bf16x8 ah[4], am[4], al[4];
#pragma unroll
    for (int mi = 0; mi < 4; ++mi) {
      int r = wm * 64 + mi * 16 + l15;
      ah[mi] = *(const bf16x8*)&Ahs[r][g * 8];
      am[mi] = *(const bf16x8*)&Ams[r][g * 8];
      al[mi] = *(const bf16x8*)&Als[r][g * 8];
    }
#pragma unroll
    for (int ni = 0; ni < 4; ++ni) {
      int r = wn * 64 + ni * 16 + l15;
      bf16x8 bb;
      bb = *(const bf16x8*)&Bhs[r][g * 8];   // xh*wh + xm*wh + xl*wh
#pragma unroll
      for (int mi = 0; mi < 4; ++mi) acc[mi][ni] = mfma16(ah[mi], bb, acc[mi][ni]);
#pragma unroll
      for (int mi = 0; mi < 4; ++mi) acc[mi][ni] = mfma16(am[mi], bb, acc[mi][ni]);
#pragma unroll
      for (int mi = 0; mi < 4; ++mi) acc[mi][ni] = mfma16(al[mi], bb, acc[mi][ni]);
      bb = *(const bf16x8*)&Bms[r][g * 8];   // xh*wm + xm*wm
#pragma unroll
      for (int mi = 0; mi < 4; ++mi) acc[mi][ni] = mfma16(ah[mi], bb, acc[mi][ni]);
#pragma unroll
      for (int mi = 0; mi < 4; ++mi) acc[mi][ni] = mfma16(am[mi], bb, acc[mi][ni]);
      bb = *(const bf16x8*)&Bls[r][g * 8];   // xh*wl
#pragma unroll
      for (int mi = 0; mi < 4; ++mi) acc[mi][ni] = mfma16(ah[mi], bb, acc[mi][ni]);
    }
    __syncthreads();
  }
#pragma unroll
  for (int mi = 0; mi < 4; ++mi)
#pragma unroll
    for (int ni = 0; ni < 4; ++ni) {
      int c = col0 + wn * 64 + ni * 16 + l15;
      float b = bias[c];
#pragma unroll
      for (int reg = 0; reg < 4; ++reg) {
        long r = row0 + wm * 64 + mi * 16 + g * 4 + reg;
        int t = (int)(r % T_STEPS);
        int n = (int)(r / T_STEPS);
        out[((long)t * NB + n) * HID + c] = acc[mi][ni][reg] + b;
      }
    }
}

// ---------------------------------------------------------------------------
// Recurrent step (MFMA): inp = s_prev @ W_rec + b_rec + xin_t -> LIF1.
// 64x64 tile, BK=64, 4 waves each 32x32. grid (4,16).
// ---------------------------------------------------------------------------
__global__ __launch_bounds__(256) void step_mfma(
    const unsigned short* __restrict__ Sprev,
    const unsigned short* __restrict__ Bh, const unsigned short* __restrict__ Bm,
    const unsigned short* __restrict__ Bl, const float* __restrict__ b_rec,
    const float* __restrict__ xin_t, float* __restrict__ v1,
    unsigned short* __restrict__ Sout) {
  __shared__ unsigned short As[64][72], Bhs[64][72], Bms[64][72], Bls[64][72];
  const int tid = threadIdx.x;
  const int w = tid >> 6, lane = tid & 63;
  const int wm = w >> 1, wn = w & 1;
  const int l15 = lane & 15, g = lane >> 4;
  const int row0 = blockIdx.x * 64;
  const int col0 = blockIdx.y * 64;
  f32x4 acc[2][2];
  const f32x4 zf = {0.f, 0.f, 0.f, 0.f};
#pragma unroll
  for (int mi = 0; mi < 2; ++mi)
#pragma unroll
    for (int ni = 0; ni < 2; ++ni) acc[mi][ni] = zf;

  for (int kt = 0; kt < HID; kt += 64) {
#pragma unroll
    for (int i = 0; i < 2; ++i) {
      int slot = tid + 256 * i;            // 0..511
      int r = slot >> 3, kk = (slot & 7) * 8;
      *(uint4*)&As[r][kk] = *(const uint4*)(Sprev + (long)(row0 + r) * HID + kt + kk);
      long gi = (long)(col0 + r) * HID + kt + kk;
      *(uint4*)&Bhs[r][kk] = *(const uint4*)(Bh + gi);
      *(uint4*)&Bms[r][kk] = *(const uint4*)(Bm + gi);
      *(uint4*)&Bls[r][kk] = *(const uint4*)(Bl + gi);
    }
    __syncthreads();
#pragma unroll
    for (int ks = 0; ks < 2; ++ks) {
      bf16x8 af[2];
#pragma unroll
      for (int mi = 0; mi < 2; ++mi)
        af[mi] = *(const bf16x8*)&As[wm * 32 + mi * 16 + l15][ks * 32 + g * 8];
#pragma unroll
      for (int ni = 0; ni < 2; ++ni) {
        int r = wn * 32 + ni * 16 + l15;
        bf16x8 bb;
        bb = *(const bf16x8*)&Bhs[r][ks * 32 + g * 8];
#pragma unroll
        for (int mi = 0; mi < 2; ++mi) acc[mi][ni] = mfma16(af[mi], bb, acc[mi][ni]);
        bb = *(const bf16x8*)&Bms[r][ks * 32 + g * 8];
#pragma unroll
        for (int mi = 0; mi < 2; ++mi) acc[mi][ni] = mfma16(af[mi], bb, acc[mi][ni]);
        bb = *(const bf16x8*)&Bls[r][ks * 32 + g * 8];
#pragma unroll
        for (int mi = 0; mi < 2; ++mi) acc[mi][ni] = mfma16(af[mi], bb, acc[mi][ni]);
      }
    }
    __syncthreads();
  }
#pragma unroll
  for (int mi = 0; mi < 2; ++mi)
#pragma unroll
    for (int ni = 0; ni < 2; ++ni) {
      int c = col0 + wn * 32 + ni * 16 + l15;
      float br = b_rec[c];
#pragma unroll
      for (int reg = 0; reg < 4; ++reg) {
        int n = row0 + wm * 32 + mi * 16 + g * 4 + reg;
        long idx = (long)n * HID + c;
        float inp = acc[mi][ni][reg] + br + xin_t[idx];
        float v = v1[idx];
        float h = v + (inp - v) * 0.5f;
        bool sp = (h >= 1.0f);
        v1[idx] = sp ? 0.0f : h;
        Sout[idx] = sp ? 0x3F80u : 0u;
      }
    }
}

// LIF1 at t=0: inp = xin[0] + b_rec, v1 starts at 0.
__global__ __launch_bounds__(256) void lif_prologue(
    const float* __restrict__ xin0, const float* __restrict__ b_rec,
    float* __restrict__ v1, unsigned short* __restrict__ s0) {
  long id = (long)blockIdx.x * 256 + threadIdx.x;
  float inp = xin0[id] + b_rec[id & (HID - 1)];
  float h = inp * 0.5f;
  bool sp = (h >= 1.0f);
  v1[id] = sp ? 0.0f : h;
  s0[id] = sp ? 0x3F80u : 0u;
}

// LIF2: per-(n,h) scan over t: z -> feat spikes (bf16 0/1).
__global__ __launch_bounds__(256) void lif2_kernel(
    const float* __restrict__ z, unsigned short* __restrict__ feat) {
  long id = (long)blockIdx.x * 256 + threadIdx.x;
  float v = 0.0f;
  for (int t = 0; t < T_STEPS; ++t) {
    float x = z[(long)t * NH + id];
    float h = v + (x - v) * 0.5f;
    bool sp = (h >= 1.0f);
    v = sp ? 0.0f : h;
    feat[(long)t * NH + id] = sp ? 0x3F80u : 0u;
  }
}

// LayerNorm over last dim (1024), in place. One block (256 thr) per row.
__global__ __launch_bounds__(256) void ln_kernel(float* __restrict__ y,
                                                 const float* __restrict__ g,
                                                 const float* __restrict__ b) {
  __shared__ float red[4];
  long row = blockIdx.x;
  float* p = y + row * HID;
  int tid = threadIdx.x;
  float x[4];
#pragma unroll
  for (int i = 0; i < 4; ++i) x[i] = p[tid + 256 * i];
  float s = x[0] + x[1] + x[2] + x[3];
#pragma unroll
  for (int m = 32; m; m >>= 1) s += __shfl_xor(s, m, 64);
  if ((tid & 63) == 0) red[tid >> 6] = s;
  __syncthreads();
  float mu = (red[0] + red[1] + red[2] + red[3]) * (1.0f / HID);
  __syncthreads();
  float r0 = x[0] - mu, r1 = x[1] - mu, r2 = x[2] - mu, r3 = x[3] - mu;
  float v = r0 * r0 + r1 * r1 + r2 * r2 + r3 * r3;
#pragma unroll
  for (int m = 32; m; m >>= 1) v += __shfl_xor(v, m, 64);
  if ((tid & 63) == 0) red[tid >> 6] = v;
  __syncthreads();
  float var = (red[0] + red[1] + red[2] + red[3]) * (1.0f / HID);
  float inv = 1.0f / sqrtf(var + 1e-5f);
#pragma unroll
  for (int i = 0; i < 4; ++i) {
    int h = tid + 256 * i;
    p[h] = (x[i] - mu) * inv * g[h] + b[h];
  }
}

// Third LIF over T fused with mean over T.
__global__ __launch_bounds__(256) void lifc_kernel(
    const float* __restrict__ y, float* __restrict__ sbar) {
  long id = (long)blockIdx.x * 256 + threadIdx.x;
  float v = 0.0f, acc = 0.0f;
  for (int t = 0; t < T_STEPS; ++t) {
    float x = y[(long)t * NH + id];
    float h = v + (x - v) * 0.5f;
    if (h >= 1.0f) {
      acc += 1.0f;
      v = 0.0f;
    } else {
      v = h;
    }
  }
  sbar[id] = acc * (1.0f / T_STEPS);
}

// out[n,j] = sbar[n,:] @ W_out[:,j] + b_out[j]
__global__ __launch_bounds__(64) void out_kernel(
    const float* __restrict__ sbar, const float* __restrict__ Wout,
    const float* __restrict__ bout, float* __restrict__ out) {
  int n = blockIdx.x, j = threadIdx.x;
  if (j >= NCLS) return;
  const float* s = sbar + (long)n * HID;
  float a0 = 0.f, a1 = 0.f, a2 = 0.f, a3 = 0.f;
  for (int k = 0; k < HID; k += 4) {
    a0 += s[k + 0] * Wout[(k + 0) * NCLS + j];
    a1 += s[k + 1] * Wout[(k + 1) * NCLS + j];
    a2 += s[k + 2] * Wout[(k + 2) * NCLS + j];
    a3 += s[k + 3] * Wout[(k + 3) * NCLS + j];
  }
  out[n * NCLS + j] = ((a0 + a1) + (a2 + a3)) + bout[j];
}

// ---------------------------------------------------------------------------
extern "C" void kernel_launch(void* const* d_in, const int* in_sizes, int n_in,
                              void* d_out, int out_size, void* d_ws,
                              size_t ws_size, hipStream_t stream) {
  const float* x = (const float*)d_in[0];
  const float* W_in = (const float*)d_in[1];
  const float* b_in = (const float*)d_in[2];
  const float* W_rec = (const float*)d_in[3];
  const float* b_rec = (const float*)d_in[4];
  const float* W2 = (const float*)d_in[5];
  const float* b2 = (const float*)d_in[6];
  const float* W3 = (const float*)d_in[7];
  const float* b3 = (const float*)d_in[8];
  const float* ln_g = (const float*)d_in[9];
  const float* ln_b = (const float*)d_in[10];
  const float* W_out = (const float*)d_in[11];
  const float* b_out = (const float*)d_in[12];
  float* out = (float*)d_out;
  (void)in_sizes; (void)n_in; (void)out_size; (void)ws_size;

  // Workspace plan (~183 MB total; round-2's known-good footprint was 223 MB):
  //   xin buffer [TNH f32] holds: xin -> (after scan) z -> (after lif2) y
  //   s1  buffer [TNH u16] holds: s1 spikes -> (after z-GEMM) feat spikes
  char* ws = (char*)d_ws;
  size_t off = 0;
  auto carve = [&](size_t bytes) -> void* {
    void* p = (void*)(ws + off);
    off += (bytes + 255) & ~(size_t)255;
    return p;
  };
  unsigned short* wih = (unsigned short*)carve((size_t)HID * CINP * 2);
  unsigned short* wim = (unsigned short*)carve((size_t)HID * CINP * 2);
  unsigned short* wil = (unsigned short*)carve((size_t)HID * CINP * 2);
  unsigned short* wrh = (unsigned short*)carve((size_t)HID * HID * 2);
  unsigned short* wrm = (unsigned short*)carve((size_t)HID * HID * 2);
  unsigned short* wrl = (unsigned short*)carve((size_t)HID * HID * 2);
  unsigned short* w2h = (unsigned short*)carve((size_t)HID * HID * 2);
  unsigned short* w2m = (unsigned short*)carve((size_t)HID * HID * 2);
  unsigned short* w2l = (unsigned short*)carve((size_t)HID * HID * 2);
  unsigned short* w3h = (unsigned short*)carve((size_t)HID * HID * 2);
  unsigned short* w3m = (unsigned short*)carve((size_t)HID * HID * 2);
  unsigned short* w3l = (unsigned short*)carve((size_t)HID * HID * 2);
  float* xin = (float*)carve((size_t)TNH * 4);            // xin / z / y
  unsigned short* s1 = (unsigned short*)carve((size_t)TNH * 2);  // s1 / feat
  float* v1 = (float*)carve((size_t)NH * 4);
  float* sbar = (float*)carve((size_t)NH * 4);

  // weight splits (transpose to [N][K], exact hi/mid/lo)
  split_w<<<dim3(CINP / 32, HID / 32), 256, 0, stream>>>(W_in, wih, wim, wil, CIN, CINP);
  split_w<<<dim3(HID / 32, HID / 32), 256, 0, stream>>>(W_rec, wrh, wrm, wrl, HID, HID);
  split_w<<<dim3(HID / 32, HID / 32), 256, 0, stream>>>(W2, w2h, w2m, w2l, HID, HID);
  split_w<<<dim3(HID / 32, HID / 32), 256, 0, stream>>>(W3, w3h, w3m, w3l, HID, HID);

  // xin[t][n][h] = x @ W_in + b_in  (6-product exact-split MFMA)
  gemm_x6<<<dim3(25600 / 128, HID / 128), 256, 0, stream>>>(x, wih, wim, wil, b_in, xin);

  // t=0 prologue, then 99 MFMA recurrent steps (s1 only)
  lif_prologue<<<dim3(NH / 256), 256, 0, stream>>>(xin, b_rec, v1, s1);
  for (int t = 1; t < T_STEPS; ++t) {
    step_mfma<<<dim3(NB / 64, HID / 64), 256, 0, stream>>>(
        s1 + (size_t)(t - 1) * NH, wrh, wrm, wrl, b_rec, xin + (size_t)t * NH,
        v1, s1 + (size_t)t * NH);
  }

  // z = s1_all @ W2 + b2 (parallel over t) -> overwrite xin (dead after scan)
  gemm_sw3<<<dim3(25600 / 128, HID / 128), 256, 0, stream>>>(s1, w2h, w2m, w2l, b2, xin, 25600);
  // LIF2 scan: z (in xin) -> feat spikes, overwriting s1 (dead after z-GEMM)
  lif2_kernel<<<dim3(NH / 256), 256, 0, stream>>>(xin, s1);

  // y = feat @ W3 + b3 -> back into xin (z dead after lif2), then LN
  gemm_sw3<<<dim3(25600 / 128, HID / 128), 256, 0, stream>>>(s1, w3h, w3m, w3l, b3, xin, 25600);
  ln_kernel<<<dim3(25600), 256, 0, stream>>>(xin, ln_g, ln_b);
  lifc_kernel<<<dim3(NH / 256), 256, 0, stream>>>(xin, sbar);
  out_kernel<<<dim3(NB), 64, 0, stream>>>(sbar, W_out, b_out, out);
}